// Round 5
// baseline (52.076 us; speedup 1.0000x reference)
//
#include <hip/hip_runtime.h>
#include <hip/hip_bf16.h>
#include <math.h>

typedef short short8 __attribute__((ext_vector_type(8)));
typedef float f32x4 __attribute__((ext_vector_type(4)));

#define NQ 32
#define NDOCS 8
#define QLEN 32
#define DLEN 200
#define DIM 128
#define MD 256           // total docs
#define HD_ROWS 208      // 13 tiles x 16 rows (200 real + 8 pad, pad masked)
#define HQB_ELEMS (NQ * QLEN * DIM)            // 131072 bf16
#define HDB_OFF_SHORTS HQB_ELEMS               // hdb starts right after hqb in ws

__device__ __forceinline__ short f2bf(float x) {
    union { float f; unsigned u; } v; v.f = x;
    unsigned r = v.u + 0x7FFFu + ((v.u >> 16) & 1u);  // RNE
    return (short)(r >> 16);
}

__device__ __forceinline__ short8 cvt8(float4 f0, float4 f1) {
    short8 o;
    o[0] = f2bf(f0.x); o[1] = f2bf(f0.y); o[2] = f2bf(f0.z); o[3] = f2bf(f0.w);
    o[4] = f2bf(f1.x); o[5] = f2bf(f1.y); o[6] = f2bf(f1.z); o[7] = f2bf(f1.w);
    return o;
}

// One kernel converts both inputs to bf16 in d_ws.
// blocks [0,64): hq -> hqb (16384 chunks of 8)
// blocks [64,3264): hd -> hdb with 208-row doc stride (819200 chunks)
__global__ __launch_bounds__(256) void convert_all(const float* __restrict__ hq,
                                                   const float* __restrict__ hd,
                                                   short* __restrict__ hqb,
                                                   short* __restrict__ hdb) {
    int b = blockIdx.x;
    if (b < 64) {
        int idx = b * 256 + threadIdx.x;
        const float4* p = reinterpret_cast<const float4*>(hq) + (size_t)idx * 2;
        reinterpret_cast<short8*>(hqb)[idx] = cvt8(p[0], p[1]);
    } else {
        int c = (b - 64) * 256 + threadIdx.x;          // 0..819199
        int m = c / 3200;                              // 3200 = 200 rows * 16 chunks
        int rkc = c - m * 3200;
        const float4* p = reinterpret_cast<const float4*>(hd) + (size_t)c * 2;
        reinterpret_cast<short8*>(hdb)[(size_t)m * (HD_ROWS * 16) + rkc] = cvt8(p[0], p[1]);
    }
}

// No-LDS scores kernel. grid = 1024: b = g*256 + m (same-doc blocks share an XCD).
// Block: 256 thr / 4 waves; wave w computes questions n = g*8 + w*2 + {0,1}.
// C = mfma(A=hd_frag, B=hq_frag): lane holds C[d = dt*16 + lg*4 + r][q = qt*16 + lr].
__global__ __launch_bounds__(256, 4) void colbert_scores(const short* __restrict__ hqb,
                                                         const short* __restrict__ hdb,
                                                         float* __restrict__ out) {
    const int b = blockIdx.x;
    const int m = b & 255, g = b >> 8;
    const int tid = threadIdx.x;
    const int wid = tid >> 6, lane = tid & 63;
    const int lg = lane >> 4, lr = lane & 15;
    const int n0 = g * 8 + wid * 2;

    // B-fragments (hq, bf16): 2 questions x 2 q-tiles x 4 k-slices, held across all tiles
    short8 B[2][2][4];
    #pragma unroll
    for (int nn = 0; nn < 2; ++nn)
        #pragma unroll
        for (int qt = 0; qt < 2; ++qt)
            #pragma unroll
            for (int s = 0; s < 4; ++s)
                B[nn][qt][s] = *reinterpret_cast<const short8*>(
                    hqb + ((size_t)((n0 + nn) * QLEN + qt * 16 + lr) * DIM + s * 32 + lg * 8));

    const short* hdm = hdb + (size_t)m * (HD_ROWS * DIM);
    const short* arow = hdm + (size_t)lr * DIM + lg * 8;   // lane's A base (row lr, k-slice lg)

    float qmax[2][2];
    #pragma unroll
    for (int nn = 0; nn < 2; ++nn)
        #pragma unroll
        for (int qt = 0; qt < 2; ++qt) qmax[nn][qt] = -INFINITY;

    #pragma unroll 1
    for (int dt = 0; dt < 13; ++dt) {
        // A-fragments for this 16-row d-tile, shared across both n and both qt
        short8 A_[4];
        #pragma unroll
        for (int s = 0; s < 4; ++s)
            A_[s] = *reinterpret_cast<const short8*>(arow + (size_t)dt * (16 * DIM) + s * 32);

        f32x4 acc[2][2];
        #pragma unroll
        for (int nn = 0; nn < 2; ++nn)
            #pragma unroll
            for (int qt = 0; qt < 2; ++qt) acc[nn][qt] = (f32x4){0.f, 0.f, 0.f, 0.f};

        #pragma unroll
        for (int s = 0; s < 4; ++s)
            #pragma unroll
            for (int nn = 0; nn < 2; ++nn)
                #pragma unroll
                for (int qt = 0; qt < 2; ++qt)
                    acc[nn][qt] = __builtin_amdgcn_mfma_f32_16x16x32_bf16(
                        A_[s], B[nn][qt][s], acc[nn][qt], 0, 0, 0);

        // lane's d = dt*16 + lg*4 + r; tile 12 has valid d only for lg < 2 (rows 192..199)
        const bool valid = (dt < 12) | (lg < 2);
        if (valid) {
            #pragma unroll
            for (int nn = 0; nn < 2; ++nn)
                #pragma unroll
                for (int qt = 0; qt < 2; ++qt)
                    qmax[nn][qt] = fmaxf(qmax[nn][qt],
                        fmaxf(fmaxf(acc[nn][qt][0], acc[nn][qt][1]),
                              fmaxf(acc[nn][qt][2], acc[nn][qt][3])));
        }
    }

    // max over d: combine the 4 lg groups (lanes ^16, ^32)
    #pragma unroll
    for (int off = 16; off <= 32; off <<= 1)
        #pragma unroll
        for (int nn = 0; nn < 2; ++nn)
            #pragma unroll
            for (int qt = 0; qt < 2; ++qt)
                qmax[nn][qt] = fmaxf(qmax[nn][qt], __shfl_xor(qmax[nn][qt], off, 64));

    // mean over q: qt0 + qt1, then sum across the 16 lr lanes
    float s0 = qmax[0][0] + qmax[0][1];
    float s1 = qmax[1][0] + qmax[1][1];
    #pragma unroll
    for (int off = 1; off <= 8; off <<= 1) {
        s0 += __shfl_xor(s0, off, 64);
        s1 += __shfl_xor(s1, off, 64);
    }
    if (lane == 0) {
        out[(size_t)n0 * MD + m] = s0 * (1.0f / 32.0f);
        out[(size_t)(n0 + 1) * MD + m] = s1 * (1.0f / 32.0f);
    }
}

// loss = mean_n( logsumexp(row_n) - row_n[8n] )
__global__ __launch_bounds__(256) void colbert_loss(const float* __restrict__ scores,
                                                    float* __restrict__ loss_out) {
    __shared__ float terms[NQ];
    const int tid = threadIdx.x;
    const int wid = tid >> 6, lane = tid & 63;
    for (int n = wid; n < NQ; n += 4) {
        const float* row = scores + n * MD;
        float v0 = row[lane], v1 = row[64 + lane], v2 = row[128 + lane], v3 = row[192 + lane];
        float mx = fmaxf(fmaxf(v0, v1), fmaxf(v2, v3));
        #pragma unroll
        for (int off = 1; off < 64; off <<= 1) mx = fmaxf(mx, __shfl_xor(mx, off, 64));
        float s = expf(v0 - mx) + expf(v1 - mx) + expf(v2 - mx) + expf(v3 - mx);
        #pragma unroll
        for (int off = 1; off < 64; off <<= 1) s += __shfl_xor(s, off, 64);
        if (lane == 0) terms[n] = (mx + logf(s)) - row[n * NDOCS];
    }
    __syncthreads();
    if (tid == 0) {
        float acc = 0.f;
        #pragma unroll
        for (int n = 0; n < NQ; ++n) acc += terms[n];
        loss_out[0] = acc * (1.0f / NQ);
    }
}

extern "C" void kernel_launch(void* const* d_in, const int* in_sizes, int n_in,
                              void* d_out, int out_size, void* d_ws, size_t ws_size,
                              hipStream_t stream) {
    const float* hq = (const float*)d_in[0];   // [32][32][128] f32
    const float* hd = (const float*)d_in[1];   // [256][200][128] f32
    float* out = (float*)d_out;                // 8192 scores + 1 loss
    short* hqb = (short*)d_ws;                             // 256 KB bf16
    short* hdb = (short*)d_ws + HDB_OFF_SHORTS;            // 256 docs x 208 rows x 128 bf16

    convert_all<<<3264, 256, 0, stream>>>(hq, hd, hqb, hdb);
    colbert_scores<<<1024, 256, 0, stream>>>(hqb, hdb, out);
    colbert_loss<<<1, 256, 0, stream>>>(out, out + NQ * MD);
}